// Round 6
// baseline (199.502 us; speedup 1.0000x reference)
//
#include <hip/hip_runtime.h>
#include <math.h>

#define DET 512
#define NB  16
#define NT  180
#define PI_D 3.14159265358979323846
#define NPAIR 89
#define PADQ 108
#define QROW 768                 // padded quads per (b,tp) row; 728 used

// ws layout (bytes):
//   [0,712)            trigp float2[89]    symmetric pair trig (c,s)
//   [TT_H,+512K)       Tt_h[d][k] f16      hi part of Toeplitz w[d-k]
//   [TT_L,+512K)       Tt_l[d][k] f16      lo part
//   [XF,+5.9M)         xf[b][t][d] f32     filtered sinogram
//   [XQ,+17.5M)        xq[b][tp][768]      f32 quads (gt[i],gu[i],gt[i+1],gu[i+1]), pad +-108
#define TT_H_OFF 8192
#define TT_L_OFF (TT_H_OFF + 512*512*2)
#define XF_OFF   (TT_L_OFF + 512*512*2)
#define XQ_OFF   (XF_OFF + NB*NT*DET*4)

typedef _Float16 half8  __attribute__((ext_vector_type(8)));
typedef _Float16 half2v __attribute__((ext_vector_type(2)));
typedef float    float4v __attribute__((ext_vector_type(4)));

__device__ inline float2 pk_fma2(float2 a, float2 b, float2 c) {
  float2 d;
  asm("v_pk_fma_f32 %0, %1, %2, %3" : "=v"(d) : "v"(a), "v"(b), "v"(c));
  return d;
}

__device__ inline void stage3(const float4* g, char* l) {
#pragma unroll
  for (int c = 0; c < 3; c++)
    __builtin_amdgcn_global_load_lds(
        (const __attribute__((address_space(1))) unsigned int*)(g + c * 256),
        (__attribute__((address_space(3))) unsigned int*)(l + c * 4096),
        16, 0, 0);
}

__global__ __launch_bounds__(256) void setup_kernel(float* __restrict__ ws) {
  int tid = threadIdx.x;
  float2* trigp = (float2*)ws;
  if (tid < NPAIR) {
    int t = tid + 1, u = 179 - tid;
    float rt = (float)t * (float)(PI_D / 180.0);
    float ru = (float)u * (float)(PI_D / 180.0);
    double ct = cos((double)rt), st = sin((double)rt);
    double cu = cos((double)ru), su = sin((double)ru);
    float2 cs;
    cs.x = (float)((ct - cu) * 0.5);
    cs.y = (float)((st + su) * 0.5);
    trigp[tid] = cs;
  }
}

// ---- Toeplitz ramp table, f16 hi/lo: Tt[d][k] = w[d-k] ----
__global__ __launch_bounds__(256) void ttab_kernel(char* __restrict__ wsb) {
  _Float16* tth = (_Float16*)(wsb + TT_H_OFF);
  _Float16* ttl = (_Float16*)(wsb + TT_L_OFF);
  int d = blockIdx.x;
  int k = threadIdx.x * 2;
#pragma unroll
  for (int c = 0; c < 2; c++) {
    int kk = k + c;
    int delta = d - kk;
    float w;
    if (delta == 0) w = 0.5f;
    else if (delta & 1) { double dd = (double)delta; w = (float)(-2.0 / (PI_D * PI_D * dd * dd)); }
    else w = 0.f;
    _Float16 h = (_Float16)w;
    tth[(size_t)d * 512 + kk] = h;
    ttl[(size_t)d * 512 + kk] = (_Float16)(w - (float)h);
  }
}

// ---------------- Filter as MFMA GEMM ----------------
// C[(b,t)][d] = sum_k x[b][k][t] * w[d-k], f16 hi/lo split (3 passes).
// Grid (8 d-tiles, 12 n-tiles, 16 b); block 256 = 4 waves, each 16t x 16d.
// A-frag: x staged in LDS  A[m=lane&15][k=q*8+j]; B-frag: Tt global b128.
__global__ __launch_bounds__(256) void filter_kernel(const float* __restrict__ x,
                                                     char* __restrict__ wsb) {
  __shared__ _Float16 xs_h[16][520];
  __shared__ _Float16 xs_l[16][520];
  const _Float16* tth = (const _Float16*)(wsb + TT_H_OFF);
  const _Float16* ttl = (const _Float16*)(wsb + TT_L_OFF);
  float* xf = (float*)(wsb + XF_OFF);

  int tid = threadIdx.x;
  int dt = blockIdx.x, nt = blockIdx.y, b = blockIdx.z;
  int t0 = nt * 16, d0 = dt * 64;

  // stage x[b][:][t0..t0+15] -> f16 hi/lo in LDS (clamp t for last tile)
  int m = tid & 15, kp = tid >> 4;
  int tS = t0 + m; if (tS > 179) tS = 179;
  const float* xb = x + (size_t)b * DET * NT + tS;
#pragma unroll 4
  for (int pass = 0; pass < 16; pass++) {
    int k = pass * 32 + kp * 2;
    float v0 = xb[(size_t)k * NT];
    float v1 = xb[(size_t)(k + 1) * NT];
    _Float16 h0 = (_Float16)v0, h1 = (_Float16)v1;
    half2v hh = {h0, h1};
    half2v ll = {(_Float16)(v0 - (float)h0), (_Float16)(v1 - (float)h1)};
    *(half2v*)&xs_h[m][k] = hh;
    *(half2v*)&xs_l[m][k] = ll;
  }
  __syncthreads();

  int lane = tid & 63, wv = tid >> 6;
  int mm = lane & 15, q = lane >> 4;
  int dw = d0 + wv * 16 + mm;
  const _Float16* th = tth + (size_t)dw * 512;
  const _Float16* tl = ttl + (size_t)dw * 512;

  float4v acc = {0.f, 0.f, 0.f, 0.f};
#pragma unroll 4
  for (int kc = 0; kc < 512; kc += 32) {
    int ka = kc + q * 8;
    half8 Ah = *(const half8*)&xs_h[mm][ka];
    half8 Al = *(const half8*)&xs_l[mm][ka];
    half8 Bh = *(const half8*)&th[ka];
    half8 Bl = *(const half8*)&tl[ka];
    acc = __builtin_amdgcn_mfma_f32_16x16x32_f16(Ah, Bh, acc, 0, 0, 0);
    acc = __builtin_amdgcn_mfma_f32_16x16x32_f16(Ah, Bl, acc, 0, 0, 0);
    acc = __builtin_amdgcn_mfma_f32_16x16x32_f16(Al, Bh, acc, 0, 0, 0);
  }

  // C/D: row(t-offset) = q*4+i, col(d) = mm
#pragma unroll
  for (int i = 0; i < 4; i++) {
    int t = t0 + q * 4 + i;
    if (t < NT) xf[((size_t)b * NT + t) * DET + dw] = acc[i];
  }
}

// ---------------- Pairing: build padded quad rows ----------------
__global__ __launch_bounds__(256) void pair_kernel(char* __restrict__ wsb) {
  const float* xf = (const float*)(wsb + XF_OFF);
  float4* xq = (float4*)(wsb + XQ_OFF);
  int tp = blockIdx.x, b = blockIdx.y;
  int t = tp + 1, u = 179 - tp;
  const float* ft = xf + ((size_t)b * NT + t) * DET;
  const float* fu = xf + ((size_t)b * NT + u) * DET;
  float4* dst = xq + ((size_t)b * NPAIR + tp) * QROW;
  for (int i = threadIdx.x; i < QROW; i += 256) {
    int d = i - PADQ;
    int d1 = d + 1;
    float at = ((unsigned)d  < 512u) ? ft[d]  : 0.f;
    float au = ((unsigned)d  < 512u) ? fu[d]  : 0.f;
    float bt = ((unsigned)d1 < 512u) ? ft[d1] : 0.f;
    float bu = ((unsigned)d1 < 512u) ? fu[d1] : 0.f;
    dst[i] = make_float4(at, au, bt, bu);
  }
}

// ---------------- Backprojection (R5 shell, R3 inner) ----------------
__global__ __launch_bounds__(256, 4) void backproj_kernel(
    const char* __restrict__ wsb, float* __restrict__ out) {
  __shared__ float4 quads[2][QROW];
  int tid = threadIdx.x;
  int b   = blockIdx.y;
  int tx  = (blockIdx.x & 7) * 32;
  int ty  = (blockIdx.x >> 3) * 32;
  int lx = tid & 31, ly = tid >> 5;

  float* ob = out + (size_t)b * DET * DET;
  int X1 = tx + lx, X2 = 511 - X1;

  int mbx = 449 - 2 * tx, mby = 449 - 2 * ty;
  if (mbx * mbx + mby * mby > 261632) {
#pragma unroll
    for (int j = 0; j < 4; j++) {
      int Y1 = ty + ly + 8 * j, Y2 = 511 - Y1;
      ob[(size_t)Y1 * DET + X1] = 0.f;
      ob[(size_t)Y1 * DET + X2] = 0.f;
      ob[(size_t)Y2 * DET + X2] = 0.f;
      ob[(size_t)Y2 * DET + X1] = 0.f;
    }
    return;
  }

  const float2* trigp = (const float2*)wsb;
  const float4* xqb = (const float4*)(wsb + XQ_OFF) + (size_t)b * NPAIR * QROW + tid;
  char* lwave = (char*)&quads[0][0] + (tid >> 6) * 1024;

  float p  = (float)(tx + lx) - 255.5f;
  float q0 = (float)(ty + ly) - 255.5f;

  int wv = tid >> 6;
  int mkx = 449 - 2 * tx;
  bool live[4];
#pragma unroll
  for (int j = 0; j < 4; j++) {
    int mky = 509 - 2 * ty - 4 * wv - 16 * j;
    live[j] = (mkx * mkx + mky * mky <= 261632);
  }

  float2 U[4], V[4], W[4], Z[4];
#pragma unroll
  for (int j = 0; j < 4; j++) {
    U[j] = make_float2(0.f, 0.f); V[j] = U[j]; W[j] = U[j]; Z[j] = U[j];
  }

  stage3(xqb, lwave);
  __syncthreads();

  for (int tp = 0; tp < NPAIR; tp++) {
    if (tp + 1 < NPAIR)
      stage3(xqb + (size_t)(tp + 1) * QROW, lwave + ((tp + 1) & 1) * (QROW * 16));
    float2 cs = trigp[tp];
    float c = cs.x, s = cs.y;
    const float2* colq2 = (const float2*)&quads[tp & 1][0];
    float inner = fmaf(-s, q0, 255.5f + (float)PADQ);
    float iyA = fmaf( c, p, inner);
    float iyB = fmaf(-c, p, inner);
    float s8 = 8.f * s;
#pragma unroll
    for (int j = 0; j < 4; j++) {
      if (live[j]) {
        int   iA = (int)iyA;
        float wA = iyA - (float)iA;
        int   iB = (int)iyB;
        float wB = iyB - (float)iB;
        float2 QAl = colq2[2 * iA],         QAh = colq2[2 * iA + 1];
        float2 QBl = colq2[2 * iB],         QBh = colq2[2 * iB + 1];
        float2 QCl = colq2[2 * (726 - iA)], QCh = colq2[2 * (726 - iA) + 1];
        float2 QDl = colq2[2 * (726 - iB)], QDh = colq2[2 * (726 - iB) + 1];
        float2 wa  = make_float2(wA, wA);
        float2 wa1 = make_float2(1.f - wA, 1.f - wA);
        float2 wb  = make_float2(wB, wB);
        float2 wb1 = make_float2(1.f - wB, 1.f - wB);
        U[j] = pk_fma2(wa1, QAl, U[j]);
        U[j] = pk_fma2(wa , QAh, U[j]);
        V[j] = pk_fma2(wb1, QBl, V[j]);
        V[j] = pk_fma2(wb , QBh, V[j]);
        W[j] = pk_fma2(wa , QCl, W[j]);
        W[j] = pk_fma2(wa1, QCh, W[j]);
        Z[j] = pk_fma2(wb , QDl, Z[j]);
        Z[j] = pk_fma2(wb1, QDh, Z[j]);
      }
      iyA -= s8; iyB -= s8;
    }
    __syncthreads();
  }

  const float* f0  = (const float*)(wsb + XF_OFF) + (size_t)b * NT * DET;
  const float* f90 = f0 + 90 * DET;
  float g0a = f0[X1], g0b = f0[X2];
  int kx = 2 * X1 - 511;
  const float SC = (float)(PI_D / 360.0);
#pragma unroll
  for (int j = 0; j < 4; j++) {
    int Y1 = ty + ly + 8 * j, Y2 = 511 - Y1;
    float g90a = f90[Y2];
    float g90b = f90[Y1];
    int ky = 2 * Y1 - 511;
    bool in = (kx * kx + ky * ky) <= 261632;
    float P1 = U[j].x + V[j].y + g0a + g90a;
    float P2 = U[j].y + V[j].x + g0b + g90a;
    float P3 = W[j].x + Z[j].y + g0b + g90b;
    float P4 = W[j].y + Z[j].x + g0a + g90b;
    ob[(size_t)Y1 * DET + X1] = in ? P1 * SC : 0.f;
    ob[(size_t)Y1 * DET + X2] = in ? P2 * SC : 0.f;
    ob[(size_t)Y2 * DET + X2] = in ? P3 * SC : 0.f;
    ob[(size_t)Y2 * DET + X1] = in ? P4 * SC : 0.f;
  }
}

extern "C" void kernel_launch(void* const* d_in, const int* in_sizes, int n_in,
                              void* d_out, int out_size, void* d_ws, size_t ws_size,
                              hipStream_t stream) {
  (void)in_sizes; (void)n_in; (void)out_size; (void)ws_size;
  const float* x = (const float*)d_in[0];
  float* out = (float*)d_out;
  float* ws  = (float*)d_ws;
  char*  wsb = (char*)d_ws;

  setup_kernel<<<1, 256, 0, stream>>>(ws);
  ttab_kernel<<<512, 256, 0, stream>>>(wsb);
  filter_kernel<<<dim3(8, 12, 16), 256, 0, stream>>>(x, wsb);
  pair_kernel<<<dim3(NPAIR, 16), 256, 0, stream>>>(wsb);
  backproj_kernel<<<dim3(64, 16), 256, 0, stream>>>(wsb, out);
}

// Round 7
// 189.178 us; speedup vs baseline: 1.0546x; 1.0546x over previous
//
#include <hip/hip_runtime.h>
#include <math.h>

#define DET 512
#define NB  16
#define NT  180
#define PI_D 3.14159265358979323846
#define NPAIR 89
#define PADQ 108

// ws layout (bytes):
//   [0,712)          trigp float2[89]   symmetric pair trig (c,s)
//   [TT,+512K)       tth[d][k] f16      Toeplitz w[d-k] * 1024
//   [XF,+5.9M)       xf[b][t][d] f32    filtered sinogram
#define TT_OFF 8192
#define XF_OFF (TT_OFF + 512*512*2)

typedef _Float16 half8  __attribute__((ext_vector_type(8)));
typedef _Float16 half2v __attribute__((ext_vector_type(2)));
typedef float    float4v __attribute__((ext_vector_type(4)));

// ---------------- init: trig + scaled f16 Toeplitz table ----------------
__global__ __launch_bounds__(256) void init_kernel(char* __restrict__ wsb) {
  int tid = threadIdx.x;
  int d = blockIdx.x;
  _Float16* tth = (_Float16*)(wsb + TT_OFF);
#pragma unroll
  for (int c = 0; c < 2; c++) {
    int k = tid * 2 + c;
    int delta = d - k;
    float w;
    if (delta == 0) w = 0.5f;
    else if (delta & 1) { double dd = (double)delta; w = (float)(-2.0 / (PI_D * PI_D * dd * dd)); }
    else w = 0.f;
    tth[(size_t)d * 512 + k] = (_Float16)(w * 1024.0f);   // scale: avoid f16 denormals
  }
  if (d == 0 && tid < NPAIR) {
    float2* trigp = (float2*)wsb;
    int t = tid + 1, u = 179 - tid;
    float rt = (float)t * (float)(PI_D / 180.0);
    float ru = (float)u * (float)(PI_D / 180.0);
    double ct = cos((double)rt), st = sin((double)rt);
    double cu = cos((double)ru), su = sin((double)ru);
    float2 cs;
    cs.x = (float)((ct - cu) * 0.5);
    cs.y = (float)((st + su) * 0.5);
    trigp[tid] = cs;
  }
}

// ---------------- Filter as MFMA GEMM, v5 ----------------
// Grid (12,16): block = (16-t tile, b); dt loop 0..7 inside (x staged ONCE).
// A (x) in LDS f16 hi/lo, chunk-XOR swizzled (conflict-free b128 reads).
// B = tth rows, f16, streamed from L2 (1 MB table). 2 indep accumulators.
__global__ __launch_bounds__(256) void filter_kernel(const float* __restrict__ x,
                                                     char* __restrict__ wsb) {
  __shared__ _Float16 xs_h[16][512];
  __shared__ _Float16 xs_l[16][512];
  const _Float16* tth = (const _Float16*)(wsb + TT_OFF);
  float* xf = (float*)(wsb + XF_OFF);

  int tid = threadIdx.x;
  int nt = blockIdx.x, b = blockIdx.y;
  int t0 = nt * 16;

  // stage x[b][:][t0+m] -> f16 hi/lo, swizzled: phys chunk = c ^ (m&7)
  int m = tid & 15, kp = tid >> 4;
  int tS = t0 + m; if (tS > 179) tS = 179;
  const float* xb = x + (size_t)b * DET * NT + tS;
#pragma unroll 4
  for (int pass = 0; pass < 16; pass++) {
    int k = pass * 32 + kp * 2;
    int c = k >> 3, h = k & 7;
    int phys = (((c ^ (m & 7)) << 3) | h);
    float v0 = xb[(size_t)k * NT];
    float v1 = xb[(size_t)(k + 1) * NT];
    _Float16 h0 = (_Float16)v0, h1 = (_Float16)v1;
    half2v hh = {h0, h1};
    half2v ll = {(_Float16)(v0 - (float)h0), (_Float16)(v1 - (float)h1)};
    *(half2v*)&xs_h[m][phys] = hh;
    *(half2v*)&xs_l[m][phys] = ll;
  }
  __syncthreads();

  int lane = tid & 63, wv = tid >> 6;
  int mm = lane & 15, q = lane >> 4;
  const _Float16* arh = &xs_h[mm][0];
  const _Float16* arl = &xs_l[mm][0];
  int e = mm & 7;

  for (int dt = 0; dt < 8; dt++) {
    int dw = dt * 64 + wv * 16 + mm;
    const _Float16* th = tth + (size_t)dw * 512;
    float4v acc0 = {0.f, 0.f, 0.f, 0.f};
    float4v acc1 = {0.f, 0.f, 0.f, 0.f};
#pragma unroll 4
    for (int kc = 0; kc < 512; kc += 32) {
      int ph = ((((kc >> 3) + q) ^ e) << 3);
      half8 Ah = *(const half8*)&arh[ph];
      half8 Al = *(const half8*)&arl[ph];
      half8 Bh = *(const half8*)&th[kc + q * 8];
      acc0 = __builtin_amdgcn_mfma_f32_16x16x32_f16(Ah, Bh, acc0, 0, 0, 0);
      acc1 = __builtin_amdgcn_mfma_f32_16x16x32_f16(Al, Bh, acc1, 0, 0, 0);
    }
#pragma unroll
    for (int i = 0; i < 4; i++) {
      int t = t0 + q * 4 + i;
      if (t < NT)
        xf[((size_t)b * NT + t) * DET + dw] = (acc0[i] + acc1[i]) * 0.0009765625f;
    }
  }
}

// ---------------- Backprojection v5: raw-column staging ----------------
// Per pair: stage ft (t=tp+1) and fu (t=179-tp) rows direct from xf via
// global_load_lds into padded regions; gathers = fused ds_read2_b32 pairs.
__global__ __launch_bounds__(256, 4) void backproj_kernel(
    const char* __restrict__ wsb, float* __restrict__ out) {
  __shared__ float cols[2][1536];   // per buf: [0,728) ft padded, [768,1496) fu padded
  int tid = threadIdx.x;
  int b   = blockIdx.y;
  int tx  = (blockIdx.x & 7) * 32;
  int ty  = (blockIdx.x >> 3) * 32;
  int lx = tid & 31, ly = tid >> 5;

  float* ob = out + (size_t)b * DET * DET;
  int X1 = tx + lx, X2 = 511 - X1;

  // block-level skip: tile (and its 3 mirrors) fully outside the circle
  int mbx = 449 - 2 * tx, mby = 449 - 2 * ty;
  if (mbx * mbx + mby * mby > 261632) {
#pragma unroll
    for (int j = 0; j < 4; j++) {
      int Y1 = ty + ly + 8 * j, Y2 = 511 - Y1;
      ob[(size_t)Y1 * DET + X1] = 0.f;
      ob[(size_t)Y1 * DET + X2] = 0.f;
      ob[(size_t)Y2 * DET + X2] = 0.f;
      ob[(size_t)Y2 * DET + X1] = 0.f;
    }
    return;
  }

  const float2* trigp = (const float2*)wsb;
  const float* xfb = (const float*)(wsb + XF_OFF) + (size_t)b * NT * DET;

  // staging geometry: waves 0,1 -> ft; waves 2,3 -> fu; each wave 1 KB
  int w = tid >> 6, l = tid & 63;
  int rsel = (w >= 2);                                   // 0=ft,1=fu
  int woff = (w & 1) * 1024 + rsel * 3072 + 432;         // bytes in buffer (16-B aligned)
  int gcol = (w & 1) * 256 + 4 * l;                      // float offset in row

  // zero everything once (pads stay zero; stages overwrite data regions only)
  for (int i = tid; i < 3072; i += 256) cols[0][i] = 0.f;
  __syncthreads();

  float p  = (float)(tx + lx) - 255.5f;
  float q0 = (float)(ty + ly) - 255.5f;

  int wv = w;
  int mkx = 449 - 2 * tx;
  bool live[4];
#pragma unroll
  for (int j = 0; j < 4; j++) {
    int mky = 509 - 2 * ty - 4 * wv - 16 * j;
    live[j] = (mkx * mkx + mky * mky <= 261632);
  }

  float A1[4] = {0,0,0,0}, A2[4] = {0,0,0,0}, A3[4] = {0,0,0,0}, A4[4] = {0,0,0,0};

  auto stage = [&](int tp, int par) {
    int trow = rsel ? (179 - tp) : (tp + 1);
    const float* g = xfb + (size_t)trow * DET + gcol;
    __builtin_amdgcn_global_load_lds(
        (const __attribute__((address_space(1))) unsigned int*)g,
        (__attribute__((address_space(3))) unsigned int*)((char*)&cols[par][0] + woff),
        16, 0, 0);
  };

  stage(0, 0);
  __syncthreads();

  for (int tp = 0; tp < NPAIR; tp++) {
    if (tp + 1 < NPAIR) stage(tp + 1, (tp + 1) & 1);
    float2 cs = trigp[tp];
    float c = cs.x, s = cs.y;
    const float* ftp_ = &cols[tp & 1][0];
    const float* fup_ = ftp_ + 768;
    float inner = fmaf(-s, q0, 255.5f + (float)PADQ);
    float iyA = fmaf( c, p, inner);
    float iyB = fmaf(-c, p, inner);
    float s8 = 8.f * s;
#pragma unroll
    for (int j = 0; j < 4; j++) {
      if (live[j]) {
        int   iA = (int)iyA;          // iy in [2,725] -> trunc == floor
        float wA = iyA - (float)iA;
        int   iB = (int)iyB;
        float wB = iyB - (float)iB;
        float vA = 1.f - wA, vB = 1.f - wB;
        float2 rAt, rBt, rAu, rBu, rCt, rDt, rCu, rDu;
        __builtin_memcpy(&rAt, &ftp_[iA], 8);
        __builtin_memcpy(&rBt, &ftp_[iB], 8);
        __builtin_memcpy(&rAu, &fup_[iA], 8);
        __builtin_memcpy(&rBu, &fup_[iB], 8);
        __builtin_memcpy(&rCt, &ftp_[726 - iA], 8);
        __builtin_memcpy(&rDt, &ftp_[726 - iB], 8);
        __builtin_memcpy(&rCu, &fup_[726 - iA], 8);
        __builtin_memcpy(&rDu, &fup_[726 - iB], 8);
        A1[j] = fmaf(vA, rAt.x, fmaf(wA, rAt.y, fmaf(vB, rBu.x, fmaf(wB, rBu.y, A1[j]))));
        A2[j] = fmaf(vB, rBt.x, fmaf(wB, rBt.y, fmaf(vA, rAu.x, fmaf(wA, rAu.y, A2[j]))));
        A3[j] = fmaf(wA, rCt.x, fmaf(vA, rCt.y, fmaf(wB, rDu.x, fmaf(vB, rDu.y, A3[j]))));
        A4[j] = fmaf(wB, rDt.x, fmaf(vB, rDt.y, fmaf(wA, rCu.x, fmaf(vA, rCu.y, A4[j]))));
      }
      iyA -= s8; iyB -= s8;
    }
    __syncthreads();
  }

  // singles t=0 (iy=X exactly) and t=90 (iy~=511-Y), mask, scale
  const float* f0  = xfb;
  const float* f90 = xfb + 90 * DET;
  float g0a = f0[X1], g0b = f0[X2];
  int kx = 2 * X1 - 511;
  const float SC = (float)(PI_D / 360.0);
#pragma unroll
  for (int j = 0; j < 4; j++) {
    int Y1 = ty + ly + 8 * j, Y2 = 511 - Y1;
    float g90a = f90[Y2];
    float g90b = f90[Y1];
    int ky = 2 * Y1 - 511;
    bool in = (kx * kx + ky * ky) <= 261632;
    float P1 = A1[j] + g0a + g90a;
    float P2 = A2[j] + g0b + g90a;
    float P3 = A3[j] + g0b + g90b;
    float P4 = A4[j] + g0a + g90b;
    ob[(size_t)Y1 * DET + X1] = in ? P1 * SC : 0.f;
    ob[(size_t)Y1 * DET + X2] = in ? P2 * SC : 0.f;
    ob[(size_t)Y2 * DET + X2] = in ? P3 * SC : 0.f;
    ob[(size_t)Y2 * DET + X1] = in ? P4 * SC : 0.f;
  }
}

extern "C" void kernel_launch(void* const* d_in, const int* in_sizes, int n_in,
                              void* d_out, int out_size, void* d_ws, size_t ws_size,
                              hipStream_t stream) {
  (void)in_sizes; (void)n_in; (void)out_size; (void)ws_size;
  const float* x = (const float*)d_in[0];
  float* out = (float*)d_out;
  char*  wsb = (char*)d_ws;

  init_kernel<<<512, 256, 0, stream>>>(wsb);
  filter_kernel<<<dim3(12, 16), 256, 0, stream>>>(x, wsb);
  backproj_kernel<<<dim3(64, 16), 256, 0, stream>>>(wsb, out);
}

// Round 10
// 186.970 us; speedup vs baseline: 1.0670x; 1.0118x over previous
//
#include <hip/hip_runtime.h>
#include <math.h>

#define DET 512
#define NB  16
#define NT  180
#define PI_D 3.14159265358979323846
#define NPAIR 89
#define PADQ 108
#define PKROW 768                // padded packed dwords per (b,tp); [108,620) data

// ws layout (bytes):
//   [0,712)        trigp float2[89]   symmetric pair trig (c,s)
//   [TT,+512K)     tth[d][k] f16      Toeplitz w[d-k] * 1024
//   [XF0,+32K)     xf0[b][512]  f32   filtered row t=0
//   [XF90,+32K)    xf90[b][512] f32   filtered row t=90
//   [PK,+4.4M)     pkf[b][tp][768] u32  packed (f16 ft[i], f16 fu[i]), pads 0
#define TT_OFF   8192
#define XF0_OFF  (TT_OFF + 512*512*2)
#define XF90_OFF (XF0_OFF + 32768)
#define PK_OFF   (XF90_OFF + 32768)

typedef _Float16 half8  __attribute__((ext_vector_type(8)));
typedef _Float16 half2v __attribute__((ext_vector_type(2)));
typedef float    float4v __attribute__((ext_vector_type(4)));

// f32 acc += f32 w * f16-half(pk)   (VOP3P mix, full-rate)
__device__ inline void fmix_lo(float& acc, float w, unsigned int pk) {
  asm("v_fma_mix_f32 %0, %1, %2, %0 op_sel_hi:[0,1,0]"
      : "+v"(acc) : "v"(w), "v"(pk));
}
__device__ inline void fmix_hi(float& acc, float w, unsigned int pk) {
  asm("v_fma_mix_f32 %0, %1, %2, %0 op_sel:[0,1,0] op_sel_hi:[0,1,0]"
      : "+v"(acc) : "v"(w), "v"(pk));
}

// ---------------- init: trig + scaled f16 Toeplitz table ----------------
__global__ __launch_bounds__(256) void init_kernel(char* __restrict__ wsb) {
  int tid = threadIdx.x;
  int d = blockIdx.x;
  _Float16* tth = (_Float16*)(wsb + TT_OFF);
#pragma unroll
  for (int c = 0; c < 2; c++) {
    int k = tid * 2 + c;
    int delta = d - k;
    float w;
    if (delta == 0) w = 0.5f;
    else if (delta & 1) { double dd = (double)delta; w = (float)(-2.0 / (PI_D * PI_D * dd * dd)); }
    else w = 0.f;
    tth[(size_t)d * 512 + k] = (_Float16)(w * 1024.0f);   // scale: avoid f16 denormals
  }
  if (d == 0 && tid < NPAIR) {
    float2* trigp = (float2*)wsb;
    int t = tid + 1, u = 179 - tid;
    float rt = (float)t * (float)(PI_D / 180.0);
    float ru = (float)u * (float)(PI_D / 180.0);
    double ct = cos((double)rt), st = sin((double)rt);
    double cu = cos((double)ru), su = sin((double)ru);
    float2 cs;
    cs.x = (float)((ct - cu) * 0.5);
    cs.y = (float)((st + su) * 0.5);
    trigp[tid] = cs;
  }
}

// ---------------- Filter (MFMA GEMM) + fused f16 pair-packing ----------------
// Grid (12,16). Block p<11 angle rows m: m<8 -> t=8p+1+m ; m>=8 -> t=164-8p+m,
// so pair tp=8p+mp lives in rows (mp, 15-mp): t=8p+mp+1, u=179-8p-mp.
// Block 11: rows {89, 91, 0, 90} = pair tp=88 (rows 0,1) + singles t=0 (row 2),
// t=90 (row 3). Coverage: 1..88 + 92..179 + {89,91,0,90} = all 180, once.
__global__ __launch_bounds__(256) void filter_kernel(const float* __restrict__ x,
                                                     char* __restrict__ wsb) {
  __shared__ _Float16 xs_h[16][512];
  __shared__ _Float16 xs_l[16][512];
  __shared__ float xfs[16][65];
  const _Float16* tth = (const _Float16*)(wsb + TT_OFF);
  unsigned int* pkg = (unsigned int*)(wsb + PK_OFF);

  int tid = threadIdx.x;
  int p = blockIdx.x, b = blockIdx.y;

  // ---- stage x columns for this block's 16 angles (f16 hi/lo, XOR-swizzled)
  int m = tid & 15, kp = tid >> 4;
  int tS;
  if (p < 11) tS = (m < 8) ? (8 * p + 1 + m) : (164 - 8 * p + m);
  else        tS = (m == 0) ? 89 : ((m == 1) ? 91 : ((m == 3) ? 90 : 0));
  const float* xb = x + (size_t)b * DET * NT + tS;
#pragma unroll 4
  for (int pass = 0; pass < 16; pass++) {
    int k = pass * 32 + kp * 2;
    int c = k >> 3, h = k & 7;
    int phys = (((c ^ (m & 7)) << 3) | h);
    float v0 = xb[(size_t)k * NT];
    float v1 = xb[(size_t)(k + 1) * NT];
    _Float16 h0 = (_Float16)v0, h1 = (_Float16)v1;
    half2v hh = {h0, h1};
    half2v ll = {(_Float16)(v0 - (float)h0), (_Float16)(v1 - (float)h1)};
    *(half2v*)&xs_h[m][phys] = hh;
    *(half2v*)&xs_l[m][phys] = ll;
  }
  __syncthreads();

  // ---- zero pkf pads for this block's pairs (once)
  int nprb = (p < 11) ? 8 : 1;
  int tpb0 = (p < 11) ? 8 * p : 88;
  {
    int idx = (tid < 108) ? tid : (620 + (tid - 108));   // 108 low + 148 high = 256
    for (int pr = 0; pr < nprb; pr++)
      pkg[((size_t)b * NPAIR + tpb0 + pr) * PKROW + idx] = 0u;
  }

  int lane = tid & 63, wv = tid >> 6;
  int mm = lane & 15, q = lane >> 4;
  const _Float16* arh = &xs_h[mm][0];
  const _Float16* arl = &xs_l[mm][0];
  int e = mm & 7;
  int mp = tid >> 5, cc = (tid & 31) * 2;               // pack assignment
  int rT = (p < 11) ? mp : 0;
  int rU = (p < 11) ? (15 - mp) : 1;
  int tpp = (p < 11) ? (8 * p + mp) : 88;
  bool dopack = (p < 11) || (mp == 0);

  for (int dt = 0; dt < 8; dt++) {
    int dw = dt * 64 + wv * 16 + mm;
    const _Float16* th = tth + (size_t)dw * 512;
    float4v acc0 = {0.f, 0.f, 0.f, 0.f};
    float4v acc1 = {0.f, 0.f, 0.f, 0.f};
#pragma unroll 4
    for (int kc = 0; kc < 512; kc += 32) {
      int ph = ((((kc >> 3) + q) ^ e) << 3);
      half8 Ah = *(const half8*)&arh[ph];
      half8 Al = *(const half8*)&arl[ph];
      half8 Bh = *(const half8*)&th[kc + q * 8];
      acc0 = __builtin_amdgcn_mfma_f32_16x16x32_f16(Ah, Bh, acc0, 0, 0, 0);
      acc1 = __builtin_amdgcn_mfma_f32_16x16x32_f16(Al, Bh, acc1, 0, 0, 0);
    }
    if (dt > 0) __syncthreads();       // previous pack finished reading xfs
#pragma unroll
    for (int i = 0; i < 4; i++)
      xfs[q * 4 + i][wv * 16 + mm] = (acc0[i] + acc1[i]) * 0.0009765625f;
    __syncthreads();
    // pack 8 pairs x 64 cols -> pkf
    if (dopack) {
      float ft0 = xfs[rT][cc], ft1 = xfs[rT][cc + 1];
      float fu0 = xfs[rU][cc], fu1 = xfs[rU][cc + 1];
      auto p0 = __builtin_amdgcn_cvt_pkrtz(ft0, fu0);   // __fp16 x2: lo=ft, hi=fu
      auto p1 = __builtin_amdgcn_cvt_pkrtz(ft1, fu1);
      uint2 dstv;
      __builtin_memcpy(&dstv.x, &p0, 4);
      __builtin_memcpy(&dstv.y, &p1, 4);
      *(uint2*)&pkg[((size_t)b * NPAIR + tpp) * PKROW + PADQ + dt * 64 + cc] = dstv;
    }
    // singles rows (f32) from block 11: row 2 = t=0, row 3 = t=90
    if (p == 11 && tid < 64) {
      float* f0  = (float*)(wsb + XF0_OFF)  + (size_t)b * DET;
      float* f90 = (float*)(wsb + XF90_OFF) + (size_t)b * DET;
      f0[dt * 64 + tid]  = xfs[2][tid];
      f90[dt * 64 + tid] = xfs[3][tid];
    }
  }
}

// ---------------- Backprojection v6: f16-packed columns + fma_mix ----------------
__global__ __launch_bounds__(256, 4) void backproj_kernel(
    const char* __restrict__ wsb, float* __restrict__ out) {
  __shared__ unsigned int pk[2][PKROW];
  int tid = threadIdx.x;
  int b   = blockIdx.y;
  int tx  = (blockIdx.x & 7) * 32;
  int ty  = (blockIdx.x >> 3) * 32;
  int lx = tid & 31, ly = tid >> 5;

  float* ob = out + (size_t)b * DET * DET;
  int X1 = tx + lx, X2 = 511 - X1;

  // block-level skip: tile (and its 3 mirrors) fully outside the circle
  int mbx = 449 - 2 * tx, mby = 449 - 2 * ty;
  if (mbx * mbx + mby * mby > 261632) {
#pragma unroll
    for (int j = 0; j < 4; j++) {
      int Y1 = ty + ly + 8 * j, Y2 = 511 - Y1;
      ob[(size_t)Y1 * DET + X1] = 0.f;
      ob[(size_t)Y1 * DET + X2] = 0.f;
      ob[(size_t)Y2 * DET + X2] = 0.f;
      ob[(size_t)Y2 * DET + X1] = 0.f;
    }
    return;
  }

  const float2* trigp = (const float2*)wsb;
  const unsigned int* pkg = (const unsigned int*)(wsb + PK_OFF) + (size_t)b * NPAIR * PKROW;

  int w = tid >> 6, l = tid & 63;

  float p_ = (float)(tx + lx) - 255.5f;
  float q0 = (float)(ty + ly) - 255.5f;

  int mkx = 449 - 2 * tx;
  bool live[4];
#pragma unroll
  for (int j = 0; j < 4; j++) {
    int mky = 509 - 2 * ty - 4 * w - 16 * j;
    live[j] = (mkx * mkx + mky * mky <= 261632);
  }

  float A1[4] = {0,0,0,0}, A2[4] = {0,0,0,0}, A3[4] = {0,0,0,0}, A4[4] = {0,0,0,0};

  auto stage = [&](int tp, int par) {
    if (w < 3) {
      const unsigned int* g = pkg + (size_t)tp * PKROW + w * 256 + l * 4;
      __builtin_amdgcn_global_load_lds(
          (const __attribute__((address_space(1))) unsigned int*)g,
          (__attribute__((address_space(3))) unsigned int*)((char*)&pk[par][0] + w * 1024),
          16, 0, 0);
    }
  };

  stage(0, 0);
  __syncthreads();

  for (int tp = 0; tp < NPAIR; tp++) {
    if (tp + 1 < NPAIR) stage(tp + 1, (tp + 1) & 1);
    float2 cs = trigp[tp];
    float c = cs.x, s = cs.y;
    const unsigned int* col = &pk[tp & 1][0];
    float inner = fmaf(-s, q0, 255.5f + (float)PADQ);
    float iyA = fmaf( c, p_, inner);
    float iyB = fmaf(-c, p_, inner);
    float s8 = 8.f * s;
#pragma unroll
    for (int j = 0; j < 4; j++) {
      if (live[j]) {
        int   iA = (int)iyA;          // iy in [2,725] -> trunc == floor
        float wA = iyA - (float)iA;
        int   iB = (int)iyB;
        float wB = iyB - (float)iB;
        float vA = 1.f - wA, vB = 1.f - wB;
        uint2 dA, dB, dMA, dMB;       // (pk[i], pk[i+1]) -> ds_read2_b32
        __builtin_memcpy(&dA,  &col[iA], 8);
        __builtin_memcpy(&dB,  &col[iB], 8);
        __builtin_memcpy(&dMA, &col[726 - iA], 8);
        __builtin_memcpy(&dMB, &col[726 - iB], 8);
        // P1: vA*ft[iA] + wA*ft[iA+1] + vB*fu[iB] + wB*fu[iB+1]
        fmix_lo(A1[j], vA, dA.x);  fmix_lo(A1[j], wA, dA.y);
        fmix_hi(A1[j], vB, dB.x);  fmix_hi(A1[j], wB, dB.y);
        // P2: vB*ft[iB] + wB*ft[iB+1] + vA*fu[iA] + wA*fu[iA+1]
        fmix_lo(A2[j], vB, dB.x);  fmix_lo(A2[j], wB, dB.y);
        fmix_hi(A2[j], vA, dA.x);  fmix_hi(A2[j], wA, dA.y);
        // P3: wA*ft[726-iA] + vA*ft[727-iA] + wB*fu[726-iB] + vB*fu[727-iB]
        fmix_lo(A3[j], wA, dMA.x); fmix_lo(A3[j], vA, dMA.y);
        fmix_hi(A3[j], wB, dMB.x); fmix_hi(A3[j], vB, dMB.y);
        // P4: wB*ft[726-iB] + vB*ft[727-iB] + wA*fu[726-iA] + vA*fu[727-iA]
        fmix_lo(A4[j], wB, dMB.x); fmix_lo(A4[j], vB, dMB.y);
        fmix_hi(A4[j], wA, dMA.x); fmix_hi(A4[j], vA, dMA.y);
      }
      iyA -= s8; iyB -= s8;
    }
    __syncthreads();
  }

  // singles t=0 (iy=X exactly) and t=90 (iy~=511-Y), mask, scale
  const float* f0  = (const float*)(wsb + XF0_OFF)  + (size_t)b * DET;
  const float* f90 = (const float*)(wsb + XF90_OFF) + (size_t)b * DET;
  float g0a = f0[X1], g0b = f0[X2];
  int kx = 2 * X1 - 511;
  const float SC = (float)(PI_D / 360.0);
#pragma unroll
  for (int j = 0; j < 4; j++) {
    int Y1 = ty + ly + 8 * j, Y2 = 511 - Y1;
    float g90a = f90[Y2];
    float g90b = f90[Y1];
    int ky = 2 * Y1 - 511;
    bool in = (kx * kx + ky * ky) <= 261632;
    float P1 = A1[j] + g0a + g90a;
    float P2 = A2[j] + g0b + g90a;
    float P3 = A3[j] + g0b + g90b;
    float P4 = A4[j] + g0a + g90b;
    ob[(size_t)Y1 * DET + X1] = in ? P1 * SC : 0.f;
    ob[(size_t)Y1 * DET + X2] = in ? P2 * SC : 0.f;
    ob[(size_t)Y2 * DET + X2] = in ? P3 * SC : 0.f;
    ob[(size_t)Y2 * DET + X1] = in ? P4 * SC : 0.f;
  }
}

extern "C" void kernel_launch(void* const* d_in, const int* in_sizes, int n_in,
                              void* d_out, int out_size, void* d_ws, size_t ws_size,
                              hipStream_t stream) {
  (void)in_sizes; (void)n_in; (void)out_size; (void)ws_size;
  const float* x = (const float*)d_in[0];
  float* out = (float*)d_out;
  char*  wsb = (char*)d_ws;

  init_kernel<<<512, 256, 0, stream>>>(wsb);
  filter_kernel<<<dim3(12, 16), 256, 0, stream>>>(x, wsb);
  backproj_kernel<<<dim3(64, 16), 256, 0, stream>>>(wsb, out);
}

// Round 11
// 183.893 us; speedup vs baseline: 1.0849x; 1.0167x over previous
//
#include <hip/hip_runtime.h>
#include <math.h>

#define DET 512
#define NB  16
#define NT  180
#define PI_D 3.14159265358979323846
#define NPAIR 89
#define PADQ 108
#define PKROW 768                // padded packed dwords per (b,tp); [108,620) data
#define NGRP 23                  // ceil(89/4) pair-groups of 4

// ws layout (bytes):
//   [0,712)        trigp float2[89]   symmetric pair trig (c,s)
//   [TT,+512K)     tth[d][k] f16      Toeplitz w[d-k] * 1024
//   [XF0,+32K)     xf0[b][512]  f32   filtered row t=0
//   [XF90,+32K)    xf90[b][512] f32   filtered row t=90
//   [PK,+4.4M)     pkf[b][tp][768] u32  packed (f16 ft[i], f16 fu[i]), pads 0
#define TT_OFF   8192
#define XF0_OFF  (TT_OFF + 512*512*2)
#define XF90_OFF (XF0_OFF + 32768)
#define PK_OFF   (XF90_OFF + 32768)

typedef _Float16 half8  __attribute__((ext_vector_type(8)));
typedef _Float16 half2v __attribute__((ext_vector_type(2)));
typedef float    float4v __attribute__((ext_vector_type(4)));

// f32 acc += f32 w * f16-half(pk)   (VOP3P mix, full-rate)
__device__ inline void fmix_lo(float& acc, float w, unsigned int pk) {
  asm("v_fma_mix_f32 %0, %1, %2, %0 op_sel_hi:[0,1,0]"
      : "+v"(acc) : "v"(w), "v"(pk));
}
__device__ inline void fmix_hi(float& acc, float w, unsigned int pk) {
  asm("v_fma_mix_f32 %0, %1, %2, %0 op_sel:[0,1,0] op_sel_hi:[0,1,0]"
      : "+v"(acc) : "v"(w), "v"(pk));
}

// ---------------- init: trig + scaled f16 Toeplitz table ----------------
__global__ __launch_bounds__(256) void init_kernel(char* __restrict__ wsb) {
  int tid = threadIdx.x;
  int d = blockIdx.x;
  _Float16* tth = (_Float16*)(wsb + TT_OFF);
#pragma unroll
  for (int c = 0; c < 2; c++) {
    int k = tid * 2 + c;
    int delta = d - k;
    float w;
    if (delta == 0) w = 0.5f;
    else if (delta & 1) { double dd = (double)delta; w = (float)(-2.0 / (PI_D * PI_D * dd * dd)); }
    else w = 0.f;
    tth[(size_t)d * 512 + k] = (_Float16)(w * 1024.0f);   // scale: avoid f16 denormals
  }
  if (d == 0 && tid < NPAIR) {
    float2* trigp = (float2*)wsb;
    int t = tid + 1, u = 179 - tid;
    float rt = (float)t * (float)(PI_D / 180.0);
    float ru = (float)u * (float)(PI_D / 180.0);
    double ct = cos((double)rt), st = sin((double)rt);
    double cu = cos((double)ru), su = sin((double)ru);
    float2 cs;
    cs.x = (float)((ct - cu) * 0.5);
    cs.y = (float)((st + su) * 0.5);
    trigp[tid] = cs;
  }
}

// ---------------- Filter (MFMA GEMM) + fused f16 pair-packing ----------------
// Grid (12,16,2). Block p<11 angle rows m: m<8 -> t=8p+1+m ; m>=8 -> t=164-8p+m,
// so pair tp=8p+mp lives in rows (mp, 15-mp). Block 11: rows {89,91,0,90} =
// pair tp=88 (rows 0,1) + singles t=0 (row 2), t=90 (row 3).
// z-half handles dt in [4z, 4z+4) (x staged in both halves).
__global__ __launch_bounds__(256) void filter_kernel(const float* __restrict__ x,
                                                     char* __restrict__ wsb) {
  __shared__ _Float16 xs_h[16][512];
  __shared__ _Float16 xs_l[16][512];
  __shared__ float xfs[16][65];
  const _Float16* tth = (const _Float16*)(wsb + TT_OFF);
  unsigned int* pkg = (unsigned int*)(wsb + PK_OFF);

  int tid = threadIdx.x;
  int p = blockIdx.x, b = blockIdx.y;
  int dt0 = blockIdx.z * 4;

  // ---- stage x columns for this block's 16 angles (f16 hi/lo, XOR-swizzled)
  int m = tid & 15, kp = tid >> 4;
  int tS;
  if (p < 11) tS = (m < 8) ? (8 * p + 1 + m) : (164 - 8 * p + m);
  else        tS = (m == 0) ? 89 : ((m == 1) ? 91 : ((m == 3) ? 90 : 0));
  const float* xb = x + (size_t)b * DET * NT + tS;
#pragma unroll 4
  for (int pass = 0; pass < 16; pass++) {
    int k = pass * 32 + kp * 2;
    int c = k >> 3, h = k & 7;
    int phys = (((c ^ (m & 7)) << 3) | h);
    float v0 = xb[(size_t)k * NT];
    float v1 = xb[(size_t)(k + 1) * NT];
    _Float16 h0 = (_Float16)v0, h1 = (_Float16)v1;
    half2v hh = {h0, h1};
    half2v ll = {(_Float16)(v0 - (float)h0), (_Float16)(v1 - (float)h1)};
    *(half2v*)&xs_h[m][phys] = hh;
    *(half2v*)&xs_l[m][phys] = ll;
  }
  __syncthreads();

  // ---- zero pkf pads for this block's pairs (once; z-halves write same zeros)
  int nprb = (p < 11) ? 8 : 1;
  int tpb0 = (p < 11) ? 8 * p : 88;
  if (blockIdx.z == 0) {
    int idx = (tid < 108) ? tid : (620 + (tid - 108));   // 108 low + 148 high = 256
    for (int pr = 0; pr < nprb; pr++)
      pkg[((size_t)b * NPAIR + tpb0 + pr) * PKROW + idx] = 0u;
  }

  int lane = tid & 63, wv = tid >> 6;
  int mm = lane & 15, q = lane >> 4;
  const _Float16* arh = &xs_h[mm][0];
  const _Float16* arl = &xs_l[mm][0];
  int e = mm & 7;
  int mp = tid >> 5, cc = (tid & 31) * 2;               // pack assignment
  int rT = (p < 11) ? mp : 0;
  int rU = (p < 11) ? (15 - mp) : 1;
  int tpp = (p < 11) ? (8 * p + mp) : 88;
  bool dopack = (p < 11) || (mp == 0);

  for (int dti = 0; dti < 4; dti++) {
    int dt = dt0 + dti;
    int dw = dt * 64 + wv * 16 + mm;
    const _Float16* th = tth + (size_t)dw * 512;
    float4v acc0 = {0.f, 0.f, 0.f, 0.f};
    float4v acc1 = {0.f, 0.f, 0.f, 0.f};
#pragma unroll 4
    for (int kc = 0; kc < 512; kc += 32) {
      int ph = ((((kc >> 3) + q) ^ e) << 3);
      half8 Ah = *(const half8*)&arh[ph];
      half8 Al = *(const half8*)&arl[ph];
      half8 Bh = *(const half8*)&th[kc + q * 8];
      acc0 = __builtin_amdgcn_mfma_f32_16x16x32_f16(Ah, Bh, acc0, 0, 0, 0);
      acc1 = __builtin_amdgcn_mfma_f32_16x16x32_f16(Al, Bh, acc1, 0, 0, 0);
    }
    if (dti > 0) __syncthreads();      // previous pack finished reading xfs
#pragma unroll
    for (int i = 0; i < 4; i++)
      xfs[q * 4 + i][wv * 16 + mm] = (acc0[i] + acc1[i]) * 0.0009765625f;
    __syncthreads();
    // pack 8 pairs x 64 cols -> pkf
    if (dopack) {
      float ft0 = xfs[rT][cc], ft1 = xfs[rT][cc + 1];
      float fu0 = xfs[rU][cc], fu1 = xfs[rU][cc + 1];
      auto p0 = __builtin_amdgcn_cvt_pkrtz(ft0, fu0);   // __fp16 x2: lo=ft, hi=fu
      auto p1 = __builtin_amdgcn_cvt_pkrtz(ft1, fu1);
      uint2 dstv;
      __builtin_memcpy(&dstv.x, &p0, 4);
      __builtin_memcpy(&dstv.y, &p1, 4);
      *(uint2*)&pkg[((size_t)b * NPAIR + tpp) * PKROW + PADQ + dt * 64 + cc] = dstv;
    }
    // singles rows (f32) from block 11: row 2 = t=0, row 3 = t=90
    if (p == 11 && tid < 64) {
      float* f0  = (float*)(wsb + XF0_OFF)  + (size_t)b * DET;
      float* f90 = (float*)(wsb + XF90_OFF) + (size_t)b * DET;
      f0[dt * 64 + tid]  = xfs[2][tid];
      f90[dt * 64 + tid] = xfs[3][tid];
    }
  }
}

// ---------------- Backprojection v7: group-of-4 staging (23 barriers) ----------------
__global__ __launch_bounds__(256, 4) void backproj_kernel(
    const char* __restrict__ wsb, float* __restrict__ out) {
  __shared__ unsigned int pk[2][4][PKROW];   // 24 KB
  int tid = threadIdx.x;
  int b   = blockIdx.y;
  int tx  = (blockIdx.x & 7) * 32;
  int ty  = (blockIdx.x >> 3) * 32;
  int lx = tid & 31, ly = tid >> 5;

  float* ob = out + (size_t)b * DET * DET;
  int X1 = tx + lx, X2 = 511 - X1;

  // block-level skip: tile (and its 3 mirrors) fully outside the circle
  int mbx = 449 - 2 * tx, mby = 449 - 2 * ty;
  if (mbx * mbx + mby * mby > 261632) {
#pragma unroll
    for (int j = 0; j < 4; j++) {
      int Y1 = ty + ly + 8 * j, Y2 = 511 - Y1;
      ob[(size_t)Y1 * DET + X1] = 0.f;
      ob[(size_t)Y1 * DET + X2] = 0.f;
      ob[(size_t)Y2 * DET + X2] = 0.f;
      ob[(size_t)Y2 * DET + X1] = 0.f;
    }
    return;
  }

  const float2* trigp = (const float2*)wsb;
  const unsigned int* pkg = (const unsigned int*)(wsb + PK_OFF) + (size_t)b * NPAIR * PKROW;

  int w = tid >> 6, l = tid & 63;

  float p_ = (float)(tx + lx) - 255.5f;
  float q0 = (float)(ty + ly) - 255.5f;

  int mkx = 449 - 2 * tx;
  bool live[4];
#pragma unroll
  for (int j = 0; j < 4; j++) {
    int mky = 509 - 2 * ty - 4 * w - 16 * j;
    live[j] = (mkx * mkx + mky * mky <= 261632);
  }

  float A1[4] = {0,0,0,0}, A2[4] = {0,0,0,0}, A3[4] = {0,0,0,0}, A4[4] = {0,0,0,0};

  // wave w stages column tp=4g+w (3x 16B-wide DMA = 3072 B)
  auto stage_group = [&](int g, int par) {
    int tp = 4 * g + w;
    if (tp < NPAIR) {
      const unsigned int* src = pkg + (size_t)tp * PKROW + l * 4;
      char* dst = (char*)&pk[par][w][0];
#pragma unroll
      for (int c3 = 0; c3 < 3; c3++)
        __builtin_amdgcn_global_load_lds(
            (const __attribute__((address_space(1))) unsigned int*)(src + c3 * 256),
            (__attribute__((address_space(3))) unsigned int*)(dst + c3 * 1024),
            16, 0, 0);
    }
  };

  stage_group(0, 0);
  __syncthreads();

  for (int g = 0; g < NGRP; g++) {
    if (g + 1 < NGRP) stage_group(g + 1, (g + 1) & 1);
    int npair = (g < NGRP - 1) ? 4 : (NPAIR - 4 * (NGRP - 1));
    for (int cgi = 0; cgi < npair; cgi++) {
      int tp = 4 * g + cgi;
      float2 cs = trigp[tp];
      float c = cs.x, s = cs.y;
      const unsigned int* col = &pk[g & 1][cgi][0];
      float inner = fmaf(-s, q0, 255.5f + (float)PADQ);
      float iyA = fmaf( c, p_, inner);
      float iyB = fmaf(-c, p_, inner);
      float s8 = 8.f * s;
#pragma unroll
      for (int j = 0; j < 4; j++) {
        if (live[j]) {
          int   iA = (int)iyA;          // iy in [2,725] -> trunc == floor
          float wA = iyA - (float)iA;
          int   iB = (int)iyB;
          float wB = iyB - (float)iB;
          float vA = 1.f - wA, vB = 1.f - wB;
          uint2 dA, dB, dMA, dMB;       // (pk[i], pk[i+1]) -> ds_read2_b32
          __builtin_memcpy(&dA,  &col[iA], 8);
          __builtin_memcpy(&dB,  &col[iB], 8);
          __builtin_memcpy(&dMA, &col[726 - iA], 8);
          __builtin_memcpy(&dMB, &col[726 - iB], 8);
          // P1: vA*ft[iA] + wA*ft[iA+1] + vB*fu[iB] + wB*fu[iB+1]
          fmix_lo(A1[j], vA, dA.x);  fmix_lo(A1[j], wA, dA.y);
          fmix_hi(A1[j], vB, dB.x);  fmix_hi(A1[j], wB, dB.y);
          // P2: vB*ft[iB] + wB*ft[iB+1] + vA*fu[iA] + wA*fu[iA+1]
          fmix_lo(A2[j], vB, dB.x);  fmix_lo(A2[j], wB, dB.y);
          fmix_hi(A2[j], vA, dA.x);  fmix_hi(A2[j], wA, dA.y);
          // P3: wA*ft[726-iA] + vA*ft[727-iA] + wB*fu[726-iB] + vB*fu[727-iB]
          fmix_lo(A3[j], wA, dMA.x); fmix_lo(A3[j], vA, dMA.y);
          fmix_hi(A3[j], wB, dMB.x); fmix_hi(A3[j], vB, dMB.y);
          // P4: wB*ft[726-iB] + vB*ft[727-iB] + wA*fu[726-iA] + vA*fu[727-iA]
          fmix_lo(A4[j], wB, dMB.x); fmix_lo(A4[j], vB, dMB.y);
          fmix_hi(A4[j], wA, dMA.x); fmix_hi(A4[j], vA, dMA.y);
        }
        iyA -= s8; iyB -= s8;
      }
    }
    __syncthreads();
  }

  // singles t=0 (iy=X exactly) and t=90 (iy~=511-Y), mask, scale
  const float* f0  = (const float*)(wsb + XF0_OFF)  + (size_t)b * DET;
  const float* f90 = (const float*)(wsb + XF90_OFF) + (size_t)b * DET;
  float g0a = f0[X1], g0b = f0[X2];
  int kx = 2 * X1 - 511;
  const float SC = (float)(PI_D / 360.0);
#pragma unroll
  for (int j = 0; j < 4; j++) {
    int Y1 = ty + ly + 8 * j, Y2 = 511 - Y1;
    float g90a = f90[Y2];
    float g90b = f90[Y1];
    int ky = 2 * Y1 - 511;
    bool in = (kx * kx + ky * ky) <= 261632;
    float P1 = A1[j] + g0a + g90a;
    float P2 = A2[j] + g0b + g90a;
    float P3 = A3[j] + g0b + g90b;
    float P4 = A4[j] + g0a + g90b;
    ob[(size_t)Y1 * DET + X1] = in ? P1 * SC : 0.f;
    ob[(size_t)Y1 * DET + X2] = in ? P2 * SC : 0.f;
    ob[(size_t)Y2 * DET + X2] = in ? P3 * SC : 0.f;
    ob[(size_t)Y2 * DET + X1] = in ? P4 * SC : 0.f;
  }
}

extern "C" void kernel_launch(void* const* d_in, const int* in_sizes, int n_in,
                              void* d_out, int out_size, void* d_ws, size_t ws_size,
                              hipStream_t stream) {
  (void)in_sizes; (void)n_in; (void)out_size; (void)ws_size;
  const float* x = (const float*)d_in[0];
  float* out = (float*)d_out;
  char*  wsb = (char*)d_ws;

  init_kernel<<<512, 256, 0, stream>>>(wsb);
  filter_kernel<<<dim3(12, 16, 2), 256, 0, stream>>>(x, wsb);
  backproj_kernel<<<dim3(64, 16), 256, 0, stream>>>(wsb, out);
}